// Round 8
// baseline (2627.942 us; speedup 1.0000x reference)
//
#include <hip/hip_runtime.h>
#include <hip/hip_bf16.h>

// ---------------------------------------------------------------------------
// AJ-RNN forward: 2-layer LSTM (B=128,T=256,D=64,H=512) with missing-value
// imputation. Round 11: TWO CHAINS PER BLOCK (latency hiding).
//  - R10 post-mortem: step 5.7us vs 0.5us compute; rendezvous skew dominates
//    and a single chain has nothing to run while waiting. Fix: 128 blocks,
//    each interleaving two independent row-group chains (rg, rg+4) that share
//    the same weight registers. Schedule H1(A),H1(B),H2(A),H2(B): each
//    stream's wait is covered by ~1us of the other stream's compute.
//  - Everything else: R10/R6 proven parts. LLC (sc0 sc1) h exchange, no cache
//    maintenance; fetch_add + s_sleep(1) wave-0 poll; float4 x; predb LDS
//    round-trip; gate-split waves; register weights; register cell state;
//    h1 LDS ping-pong per stream; load-issue + 8-MFMA cover + land.
// ---------------------------------------------------------------------------

typedef __bf16        v8bf  __attribute__((ext_vector_type(8)));
typedef float         f32x4 __attribute__((ext_vector_type(4)));
typedef unsigned int  u32x4 __attribute__((ext_vector_type(4)));

constexpr int B_ = 128, T_ = 256, D_ = 64, H_ = 512;

// workspace layout (bytes)
constexpr size_t OFF_WP1 = 0;        // packed [k0;r0] bf16 -> 2359296 B
constexpr size_t OFF_WP2 = 2359296;  // packed [k1;r1] bf16 -> 4194304 B
constexpr size_t OFF_WPP = 6553600;  // packed W bf16       ->   65536 B
constexpr size_t OFF_H1G = 6619136;  // h1 exchange bf16       131072 B
constexpr size_t OFF_H2G = 6750208;  // h2 exchange bf16       131072 B
constexpr size_t OFF_FLG = 6881280;  // 8 chains * 64 u32 =      2048 B

__device__ __forceinline__ v8bf ldv(const __hip_bfloat16* p) {
  return *reinterpret_cast<const v8bf*>(p);
}
__device__ __forceinline__ f32x4 MF(v8bf a, v8bf b, f32x4 c) {
  return __builtin_amdgcn_mfma_f32_16x16x32_bf16(a, b, c, 0, 0, 0);
}
__device__ __forceinline__ float sigf(float x) { return 1.0f / (1.0f + __expf(-x)); }
__device__ __forceinline__ float tanhfast(float x) {
  x = fminf(15.0f, fmaxf(-15.0f, x));
  float e = __expf(-2.0f * x);
  return (1.0f - e) / (1.0f + e);
}

// store straight to the device coherence point (LLC)
__device__ __forceinline__ void st_llc_u16(void* p, unsigned v) {
  asm volatile("global_store_short %0, %1, off sc0 sc1" :: "v"(p), "v"(v) : "memory");
}
__device__ __forceinline__ void vm0() {
  asm volatile("s_waitcnt vmcnt(0)" ::: "memory");
}
// issue 64B of LLC loads (bypass L1/L2); land later after vm0()
__device__ __forceinline__ void ld_llc64_issue(const char* g, u32x4& a, u32x4& b,
                                               u32x4& c, u32x4& d) {
  asm volatile(
      "global_load_dwordx4 %0, %4, off sc0 sc1\n\t"
      "global_load_dwordx4 %1, %4, off offset:16 sc0 sc1\n\t"
      "global_load_dwordx4 %2, %4, off offset:32 sc0 sc1\n\t"
      "global_load_dwordx4 %3, %4, off offset:48 sc0 sc1"
      : "=&v"(a), "=&v"(b), "=&v"(c), "=&v"(d)
      : "v"(g)
      : "memory");
}

// ---------------------------------------------------------------------------
// Pack B-operand fragments (float32 in, bf16 out):
// out[((ct*nkc + kc)*64 + lane)*8 + j] = Wcat[kc*32 + (lane>>4)*8 + j][ct*16 + (lane&15)]
// ---------------------------------------------------------------------------
__global__ __launch_bounds__(256) void pack_weights(
    const float* __restrict__ kp, const float* __restrict__ rp,
    int krows, int ncols, int nkc, int nct, __hip_bfloat16* __restrict__ out) {
  int tid = blockIdx.x * 256 + threadIdx.x;
  int total = nct * nkc * 64;
  if (tid >= total) return;
  int L  = tid & 63;
  int kc = (tid >> 6) % nkc;
  int ct = tid / (64 * nkc);
  int n  = ct * 16 + (L & 15);
  int kb = kc * 32 + (L >> 4) * 8;
  __hip_bfloat16* dst = out + (size_t)tid * 8;
#pragma unroll
  for (int j = 0; j < 8; ++j) {
    int kk = kb + j;
    float v = (kk < krows) ? kp[kk * ncols + n] : rp[(kk - krows) * ncols + n];
    dst[j] = __float2bfloat16(v);
  }
}

// zero the barrier counters (ws re-poisoned to 0xAA before every call).
// h1g/h2g need no init: every read is barrier-gated behind its producer store.
__global__ __launch_bounds__(256) void init_state(unsigned* __restrict__ flg) {
  int idx = blockIdx.x * 256 + threadIdx.x;
  if (idx < 512) flg[idx] = 0u;
}

// thread constants shared by both streams
struct TC {
  int tid, cg, w, m, q, row2, col2, c0, sw, so0, ssw;
  size_t gso;
};

// ---------------------------------------------------------------------------
// half1: wait barrier-2(t-1) -> land h2 -> pred -> cur -> z1 -> L1 gates ->
//        h1 store -> signal barrier-1(t)
// ---------------------------------------------------------------------------
__device__ __forceinline__ void half1(
    int t, const TC& tc,
    __hip_bfloat16 (*h1L)[512], __hip_bfloat16 (*h2L)[512],
    __hip_bfloat16 (*curL)[72], float (*predb)[68], float (*zb)[16][17],
    unsigned* cnt, const float* xrow, float* prow,
    const char* h2src, __hip_bfloat16* h1dst,
    const v8bf (&wpp)[16], const v8bf (&wp1)[18],
    float b0i, float b0f, float b0g, float b0o, float bD,
    float& c1v) {
  const int tid = tc.tid, m = tc.m, q = tc.q, w = tc.w;
  const int row2 = tc.row2, col2 = tc.col2, c0 = tc.c0, sw = tc.sw;
  const int so0 = tc.so0, ssw = tc.ssw;
  f32x4 z1a = {0.f,0.f,0.f,0.f}, z1b = {0.f,0.f,0.f,0.f};
  const float4 xv = *reinterpret_cast<const float4*>(xrow + t * D_ + c0);

  if (t > 0) {
    // wait barrier-2(t-1): counter == 32*(2(t-1)+2) = 64t
    if (tid < 64) {
      const unsigned tgt = 64u * (unsigned)t;
      while (__hip_atomic_load(cnt, __ATOMIC_RELAXED, __HIP_MEMORY_SCOPE_AGENT) < tgt)
        __builtin_amdgcn_s_sleep(1);
    }
    __syncthreads();
    // issue h2 loads; cover with z1-h1 chunks [0..8); land
    u32x4 sa, sb, sc2, sd;
    ld_llc64_issue(h2src + tc.gso, sa, sb, sc2, sd);
#pragma unroll
    for (int c = 0; c < 8; c += 2) {
      v8bf a0 = ldv(&h1L[m][(c * 32 + q * 8) ^ sw]);
      v8bf a1 = ldv(&h1L[m][((c + 1) * 32 + q * 8) ^ sw]);
      z1a = MF(a0, wp1[2 + c], z1a);
      z1b = MF(a1, wp1[3 + c], z1b);
    }
    vm0();
    {
      char* lb = (char*)(&h2L[row2][0]);
      *(u32x4*)(lb + ((so0 +  0) ^ ssw)) = sa;
      *(u32x4*)(lb + ((so0 + 16) ^ ssw)) = sb;
      *(u32x4*)(lb + ((so0 + 32) ^ ssw)) = sc2;
      *(u32x4*)(lb + ((so0 + 48) ^ ssw)) = sd;
    }
    __syncthreads();
    // pred = h2_{t-1} @ W + bias (wave w: cols w*16..+15)
    {
      f32x4 a0 = {0.f,0.f,0.f,0.f}, a1 = {0.f,0.f,0.f,0.f};
#pragma unroll
      for (int kc = 0; kc < 16; kc += 2) {
        v8bf x0 = ldv(&h2L[m][(kc * 32 + q * 8) ^ sw]);
        v8bf x1 = ldv(&h2L[m][((kc + 1) * 32 + q * 8) ^ sw]);
        a0 = MF(x0, wpp[kc], a0);
        a1 = MF(x1, wpp[kc + 1], a1);
      }
      a0 += a1;
#pragma unroll
      for (int r = 0; r < 4; ++r) predb[q * 4 + r][w * 16 + m] = a0[r] + bD;
    }
    __syncthreads();
  }

  // cur build; cg==0 streams pred -> d_out
  {
    float4 pv = {0.f, 0.f, 0.f, 0.f};
    if (t > 0) pv = *reinterpret_cast<const float4*>(&predb[row2][c0]);
    const float xa[4] = {xv.x, xv.y, xv.z, xv.w};
    const float pa[4] = {pv.x, pv.y, pv.z, pv.w};
#pragma unroll
    for (int j = 0; j < 4; ++j) {
      const bool missv = (t > 0) && (xa[j] == 128.0f);
      curL[row2][c0 + j] = __float2bfloat16(missv ? pa[j] : xa[j]);
    }
    if (tc.cg == 0 && t > 0)
      *reinterpret_cast<float4*>(prow + (size_t)(t - 1) * D_ + c0) = pv;
  }
  __syncthreads();

  // z1 h1 chunks [8..16) + cur chunks -> zb
  {
#pragma unroll
    for (int c = 8; c < 16; c += 2) {
      v8bf a0 = ldv(&h1L[m][(c * 32 + q * 8) ^ sw]);
      v8bf a1 = ldv(&h1L[m][((c + 1) * 32 + q * 8) ^ sw]);
      z1a = MF(a0, wp1[2 + c], z1a);
      z1b = MF(a1, wp1[3 + c], z1b);
    }
    v8bf a0 = ldv(&curL[m][q * 8]);
    v8bf a1 = ldv(&curL[m][32 + q * 8]);
    z1a = MF(a0, wp1[0], z1a);
    z1b = MF(a1, wp1[1], z1b);
    f32x4 zf = z1a + z1b;
#pragma unroll
    for (int r = 0; r < 4; ++r) zb[w][q * 4 + r][m] = zf[r];
  }
  __syncthreads();

  // L1 gates + h1_t store; drain; signal barrier-1(t)
  {
    float iv = zb[0][row2][col2] + b0i;
    float fv = zb[1][row2][col2] + b0f;
    float gv = zb[2][row2][col2] + b0g;
    float ov = zb[3][row2][col2] + b0o;
    float ig = sigf(iv), fg = sigf(fv), gg = tanhfast(gv), og = sigf(ov);
    c1v = fg * c1v + ig * gg;
    float hn = og * tanhfast(c1v);
    st_llc_u16(h1dst, (unsigned)__builtin_bit_cast(unsigned short,
                                                   __float2bfloat16(hn)));
  }
  vm0();
  __syncthreads();
  if (tid == 0)
    __hip_atomic_fetch_add(cnt, 1u, __ATOMIC_RELAXED, __HIP_MEMORY_SCOPE_AGENT);
}

// ---------------------------------------------------------------------------
// half2: z2-h2 cover -> wait barrier-1(t) -> land h1_t -> z2-h1 -> L2 gates ->
//        h2 store (or last_cell) -> signal barrier-2(t)
// ---------------------------------------------------------------------------
__device__ __forceinline__ void half2(
    int t, const TC& tc,
    __hip_bfloat16 (*h1N)[512], __hip_bfloat16 (*h2L)[512],
    float (*zb)[16][17],
    unsigned* cnt, const char* h1src,
    __hip_bfloat16* h2dst, float* lastp,
    const v8bf (&wp2)[32],
    float b1i, float b1f, float b1g, float b1o,
    float& c2v) {
  const int tid = tc.tid, m = tc.m, q = tc.q, w = tc.w;
  const int row2 = tc.row2, col2 = tc.col2, sw = tc.sw;
  const int so0 = tc.so0, ssw = tc.ssw;
  f32x4 z2a = {0.f,0.f,0.f,0.f}, z2b = {0.f,0.f,0.f,0.f};

  // pre-wait cover: z2-h2 chunks [0..8)
#pragma unroll
  for (int c = 0; c < 8; c += 2) {
    v8bf a0 = ldv(&h2L[m][(c * 32 + q * 8) ^ sw]);
    v8bf a1 = ldv(&h2L[m][((c + 1) * 32 + q * 8) ^ sw]);
    z2a = MF(a0, wp2[16 + c], z2a);
    z2b = MF(a1, wp2[17 + c], z2b);
  }
  // wait barrier-1(t): counter == 32*(2t+1)
  if (tid < 64) {
    const unsigned tgt = 32u * (2u * (unsigned)t + 1u);
    while (__hip_atomic_load(cnt, __ATOMIC_RELAXED, __HIP_MEMORY_SCOPE_AGENT) < tgt)
      __builtin_amdgcn_s_sleep(1);
  }
  __syncthreads();
  // issue h1_t loads; cover with z2-h2 chunks [8..16); land
  {
    u32x4 sa, sb, sc2, sd;
    ld_llc64_issue(h1src + tc.gso, sa, sb, sc2, sd);
#pragma unroll
    for (int c = 8; c < 16; c += 2) {
      v8bf a0 = ldv(&h2L[m][(c * 32 + q * 8) ^ sw]);
      v8bf a1 = ldv(&h2L[m][((c + 1) * 32 + q * 8) ^ sw]);
      z2a = MF(a0, wp2[16 + c], z2a);
      z2b = MF(a1, wp2[17 + c], z2b);
    }
    vm0();
    char* lb = (char*)(&h1N[row2][0]);
    *(u32x4*)(lb + ((so0 +  0) ^ ssw)) = sa;
    *(u32x4*)(lb + ((so0 + 16) ^ ssw)) = sb;
    *(u32x4*)(lb + ((so0 + 32) ^ ssw)) = sc2;
    *(u32x4*)(lb + ((so0 + 48) ^ ssw)) = sd;
  }
  __syncthreads();
  // z2 h1-half -> zb
  {
#pragma unroll
    for (int c = 0; c < 16; c += 2) {
      v8bf a0 = ldv(&h1N[m][(c * 32 + q * 8) ^ sw]);
      v8bf a1 = ldv(&h1N[m][((c + 1) * 32 + q * 8) ^ sw]);
      z2a = MF(a0, wp2[c], z2a);
      z2b = MF(a1, wp2[c + 1], z2b);
    }
    f32x4 zf = z2a + z2b;
#pragma unroll
    for (int r = 0; r < 4; ++r) zb[w][q * 4 + r][m] = zf[r];
  }
  __syncthreads();
  // L2 gates; h2 store or last_cell
  {
    float iv = zb[0][row2][col2] + b1i;
    float fv = zb[1][row2][col2] + b1f;
    float gv = zb[2][row2][col2] + b1g;
    float ov = zb[3][row2][col2] + b1o;
    float ig = sigf(iv), fg = sigf(fv), gg = tanhfast(gv), og = sigf(ov);
    c2v = fg * c2v + ig * gg;
    float hn = og * tanhfast(c2v);
    if (t == T_ - 1) {
      *lastp = hn;
    } else {
      st_llc_u16(h2dst, (unsigned)__builtin_bit_cast(unsigned short,
                                                     __float2bfloat16(hn)));
    }
  }
  if (t != T_ - 1) {
    vm0();
    __syncthreads();
    if (tid == 0)
      __hip_atomic_fetch_add(cnt, 1u, __ATOMIC_RELAXED, __HIP_MEMORY_SCOPE_AGENT);
  }
}

// ---------------------------------------------------------------------------
// Persistent recurrence kernel, 128 blocks. Block = (pr, cg): cg = 16-col
// slice (0..31); streams A (rg=pr) and B (rg=pr+4) interleaved:
//   H1(A) H1(B) H2(A) H2(B)   -- each wait covered by the other stream.
// Chains: 8 chains of 32 participants (blocks sharing pr). Monotonic counter
// barrier per chain as in R6/R10; single h buffers overwrite-safe by the
// dependence-chain argument (see R10 header).
// ---------------------------------------------------------------------------
__global__ __launch_bounds__(256, 1) void rnn_persist(
    const float* __restrict__ x,
    const __hip_bfloat16* __restrict__ Wp1,
    const __hip_bfloat16* __restrict__ Wp2,
    const __hip_bfloat16* __restrict__ WpP,
    const float* __restrict__ b0,
    const float* __restrict__ b1,
    const float* __restrict__ biasD,
    __hip_bfloat16* __restrict__ h1g,
    __hip_bfloat16* __restrict__ h2g,
    unsigned* __restrict__ flg,
    float* __restrict__ pred_out,
    float* __restrict__ last_out) {

  // h tiles: 1024B rows, XOR-swizzled (phys_byte = log_byte ^ ((row&7)<<4))
  __shared__ alignas(16) __hip_bfloat16 h1PA[16][512], h1QA[16][512], h2LA[16][512];
  __shared__ alignas(16) __hip_bfloat16 h1PB[16][512], h1QB[16][512], h2LB[16][512];
  __shared__ alignas(16) __hip_bfloat16 curLA[16][72], curLB[16][72];
  __shared__ alignas(16) float predbA[16][68], predbB[16][68];
  __shared__ float zbA[4][16][17], zbB[4][16][17];

  TC tc;
  tc.tid  = threadIdx.x;
  const int pr = blockIdx.x & 3;
  tc.cg   = blockIdx.x >> 2;
  tc.w    = tc.tid >> 6;
  const int L = tc.tid & 63;
  tc.m    = L & 15;
  tc.q    = L >> 4;
  tc.row2 = tc.tid >> 4;
  tc.col2 = tc.tid & 15;
  tc.c0   = tc.col2 * 4;
  tc.sw   = (tc.m & 7) << 3;
  tc.so0  = tc.col2 * 64;
  tc.ssw  = (tc.row2 & 7) << 4;
  tc.gso  = (size_t)tc.row2 * 1024 + tc.so0;

  const int rgA = pr, rgB = pr + 4;
  const int C = tc.cg * 16 + tc.col2;
  const int RA = rgA * 16 + tc.row2, RB = rgB * 16 + tc.row2;

  // ---- weight fragments into registers, once (shared by both streams) ----
  v8bf wpp[16], wp1[18], wp2[32];
  {
    const int ct = tc.w * 32 + tc.cg;
#pragma unroll
    for (int kc = 0; kc < 16; ++kc)
      wpp[kc] = ldv(WpP + ((size_t)(tc.w * 16 + kc) * 64 + L) * 8);
#pragma unroll
    for (int kc = 0; kc < 18; ++kc)
      wp1[kc] = ldv(Wp1 + ((size_t)(ct * 18 + kc) * 64 + L) * 8);
#pragma unroll
    for (int kc = 0; kc < 32; ++kc)
      wp2[kc] = ldv(Wp2 + ((size_t)(ct * 32 + kc) * 64 + L) * 8);
  }
  const float b0i = b0[C], b0f = b0[512 + C], b0g = b0[1024 + C], b0o = b0[1536 + C];
  const float b1i = b1[C], b1f = b1[512 + C], b1g = b1[1024 + C], b1o = b1[1536 + C];
  const float bD  = biasD[tc.w * 16 + tc.m];

  float c1A = 0.0f, c2A = 0.0f, c1B = 0.0f, c2B = 0.0f;

  const size_t rgbaseA = (size_t)rgA * 16 * H_, rgbaseB = (size_t)rgB * 16 * H_;
  const float* xrowA = x + (size_t)RA * T_ * D_;
  const float* xrowB = x + (size_t)RB * T_ * D_;
  float* prowA = pred_out + (size_t)RA * (T_ - 1) * D_;
  float* prowB = pred_out + (size_t)RB * (T_ - 1) * D_;
  unsigned* cntA = flg + rgA * 64;
  unsigned* cntB = flg + rgB * 64;
  const int hidxA = RA * H_ + C, hidxB = RB * H_ + C;
  const char* h2srcA = (const char*)(h2g + rgbaseA);
  const char* h2srcB = (const char*)(h2g + rgbaseB);
  const char* h1srcA = (const char*)(h1g + rgbaseA);
  const char* h1srcB = (const char*)(h1g + rgbaseB);

  // prologue: h1(-1)=0 (ping) and h2(-1)=0 for both streams, directly in LDS
  {
    u32x4 zz = {0u, 0u, 0u, 0u};
    u32x4* p1 = reinterpret_cast<u32x4*>(&h1PA[0][0]);
    u32x4* p2 = reinterpret_cast<u32x4*>(&h2LA[0][0]);
    u32x4* p3 = reinterpret_cast<u32x4*>(&h1PB[0][0]);
    u32x4* p4 = reinterpret_cast<u32x4*>(&h2LB[0][0]);
#pragma unroll
    for (int i = 0; i < 4; ++i) {
      p1[tc.tid * 4 + i] = zz; p2[tc.tid * 4 + i] = zz;
      p3[tc.tid * 4 + i] = zz; p4[tc.tid * 4 + i] = zz;
    }
  }
  __syncthreads();

  for (int t = 0; t < T_; ++t) {
    __hip_bfloat16 (*h1LA)[512] = (t & 1) ? h1QA : h1PA;
    __hip_bfloat16 (*h1NA)[512] = (t & 1) ? h1PA : h1QA;
    __hip_bfloat16 (*h1LB)[512] = (t & 1) ? h1QB : h1PB;
    __hip_bfloat16 (*h1NB)[512] = (t & 1) ? h1PB : h1QB;

    half1(t, tc, h1LA, h2LA, curLA, predbA, zbA, cntA, xrowA, prowA,
          h2srcA, h1g + hidxA, wpp, wp1, b0i, b0f, b0g, b0o, bD, c1A);
    half1(t, tc, h1LB, h2LB, curLB, predbB, zbB, cntB, xrowB, prowB,
          h2srcB, h1g + hidxB, wpp, wp1, b0i, b0f, b0g, b0o, bD, c1B);
    half2(t, tc, h1NA, h2LA, zbA, cntA, h1srcA,
          h2g + hidxA, last_out + hidxA, wp2, b1i, b1f, b1g, b1o, c2A);
    half2(t, tc, h1NB, h2LB, zbB, cntB, h1srcB,
          h2g + hidxB, last_out + hidxB, wp2, b1i, b1f, b1g, b1o, c2B);
  }
}

// ---------------------------------------------------------------------------
extern "C" void kernel_launch(void* const* d_in, const int* in_sizes, int n_in,
                              void* d_out, int out_size, void* d_ws, size_t ws_size,
                              hipStream_t stream) {
  const float* x    = (const float*)d_in[0];
  const float* k0   = (const float*)d_in[1];
  const float* r0   = (const float*)d_in[2];
  const float* b0   = (const float*)d_in[3];
  const float* k1   = (const float*)d_in[4];
  const float* r1   = (const float*)d_in[5];
  const float* b1   = (const float*)d_in[6];
  const float* W    = (const float*)d_in[7];
  const float* bias = (const float*)d_in[8];

  char* ws = (char*)d_ws;
  __hip_bfloat16* Wp1 = (__hip_bfloat16*)(ws + OFF_WP1);
  __hip_bfloat16* Wp2 = (__hip_bfloat16*)(ws + OFF_WP2);
  __hip_bfloat16* WpP = (__hip_bfloat16*)(ws + OFF_WPP);
  __hip_bfloat16* h1g = (__hip_bfloat16*)(ws + OFF_H1G);
  __hip_bfloat16* h2g = (__hip_bfloat16*)(ws + OFF_H2G);
  unsigned*       flg = (unsigned*)(ws + OFF_FLG);

  pack_weights<<<(128 * 18 * 64 + 255) / 256, 256, 0, stream>>>(k0, r0, 64, 2048, 18, 128, Wp1);
  pack_weights<<<(128 * 32 * 64 + 255) / 256, 256, 0, stream>>>(k1, r1, 512, 2048, 32, 128, Wp2);
  pack_weights<<<(4 * 16 * 64 + 255) / 256, 256, 0, stream>>>(W, W, 512, 64, 16, 4, WpP);
  init_state<<<2, 256, 0, stream>>>(flg);

  float* outp = (float*)d_out;
  float* last = outp + (size_t)B_ * (T_ - 1) * D_;

  rnn_persist<<<128, 256, 0, stream>>>(x, Wp1, Wp2, WpP, b0, b1, bias,
                                       h1g, h2g, flg, outp, last);
}

// Round 9
// 1554.523 us; speedup vs baseline: 1.6905x; 1.6905x over previous
//
#include <hip/hip_runtime.h>
#include <hip/hip_bf16.h>

// ---------------------------------------------------------------------------
// AJ-RNN forward: 2-layer LSTM (B=128,T=256,D=64,H=512) with missing-value
// imputation. Round 12: R10 (best, 1467us) + FLAG-ARRAY barrier (no RMW).
//  SINGLE-VARIABLE change vs R10: signal/wait mechanism only.
//   - signal: per-block ticket store to its OWN flag word (sc0 sc1, no RMW)
//     [R10: 32 blocks fetch_add ONE LLC word -> ~3k cyc serialized per barrier]
//   - wait: wave-0 coalesced 128B poll of all 32 flags + s_sleep(1) pacing
//     [R9's flag poll had NO sleep -> LLC poll storm; that was the confound]
//  Everything else R10 verbatim: pipelined covers, LLC (sc0 sc1) h exchange,
//  float4 x, predb round-trip, gate-split waves, register weights/cell state,
//  h1 LDS ping-pong, rotated z1 across the loop boundary.
// ---------------------------------------------------------------------------

typedef __bf16        v8bf  __attribute__((ext_vector_type(8)));
typedef float         f32x4 __attribute__((ext_vector_type(4)));
typedef unsigned int  u32x4 __attribute__((ext_vector_type(4)));

constexpr int B_ = 128, T_ = 256, D_ = 64, H_ = 512;

// workspace layout (bytes)
constexpr size_t OFF_WP1 = 0;        // packed [k0;r0] bf16 -> 2359296 B
constexpr size_t OFF_WP2 = 2359296;  // packed [k1;r1] bf16 -> 4194304 B
constexpr size_t OFF_WPP = 6553600;  // packed W bf16       ->   65536 B
constexpr size_t OFF_H1G = 6619136;  // h1 exchange bf16       131072 B
constexpr size_t OFF_H2G = 6750208;  // h2 exchange bf16       131072 B
constexpr size_t OFF_FLG = 6881280;  // 8 chains * 64 u32 =      2048 B

__device__ __forceinline__ v8bf ldv(const __hip_bfloat16* p) {
  return *reinterpret_cast<const v8bf*>(p);
}
__device__ __forceinline__ f32x4 MF(v8bf a, v8bf b, f32x4 c) {
  return __builtin_amdgcn_mfma_f32_16x16x32_bf16(a, b, c, 0, 0, 0);
}
__device__ __forceinline__ float sigf(float x) { return 1.0f / (1.0f + __expf(-x)); }
__device__ __forceinline__ float tanhfast(float x) {
  x = fminf(15.0f, fmaxf(-15.0f, x));
  float e = __expf(-2.0f * x);
  return (1.0f - e) / (1.0f + e);
}

// store straight to the device coherence point (LLC)
__device__ __forceinline__ void st_llc_u16(void* p, unsigned v) {
  asm volatile("global_store_short %0, %1, off sc0 sc1" :: "v"(p), "v"(v) : "memory");
}
__device__ __forceinline__ void st_flag(unsigned* p, unsigned v) {
  asm volatile("global_store_dword %0, %1, off sc0 sc1" :: "v"(p), "v"(v) : "memory");
}
__device__ __forceinline__ void vm0() {
  asm volatile("s_waitcnt vmcnt(0)" ::: "memory");
}
// issue 64B of LLC loads (bypass L1/L2); land later after vm0()
__device__ __forceinline__ void ld_llc64_issue(const char* g, u32x4& a, u32x4& b,
                                               u32x4& c, u32x4& d) {
  asm volatile(
      "global_load_dwordx4 %0, %4, off sc0 sc1\n\t"
      "global_load_dwordx4 %1, %4, off offset:16 sc0 sc1\n\t"
      "global_load_dwordx4 %2, %4, off offset:32 sc0 sc1\n\t"
      "global_load_dwordx4 %3, %4, off offset:48 sc0 sc1"
      : "=&v"(a), "=&v"(b), "=&v"(c), "=&v"(d)
      : "v"(g)
      : "memory");
}
// wave-0 poll of the chain's 32-flag line (one coalesced 128B load/iter),
// s_sleep-paced so the LLC isn't hammered while producers work.
__device__ __forceinline__ void poll_flags(const unsigned* fbase, int lane,
                                           unsigned tgt) {
  const unsigned* fp = fbase + (lane & 31);
  for (;;) {
    unsigned f;
    asm volatile("global_load_dword %0, %1, off sc0 sc1\n\ts_waitcnt vmcnt(0)"
                 : "=v"(f) : "v"(fp) : "memory");
    if (!__any((int)(f < tgt))) return;
    __builtin_amdgcn_s_sleep(1);
  }
}

// ---------------------------------------------------------------------------
// Pack B-operand fragments (float32 in, bf16 out):
// out[((ct*nkc + kc)*64 + lane)*8 + j] = Wcat[kc*32 + (lane>>4)*8 + j][ct*16 + (lane&15)]
// ---------------------------------------------------------------------------
__global__ __launch_bounds__(256) void pack_weights(
    const float* __restrict__ kp, const float* __restrict__ rp,
    int krows, int ncols, int nkc, int nct, __hip_bfloat16* __restrict__ out) {
  int tid = blockIdx.x * 256 + threadIdx.x;
  int total = nct * nkc * 64;
  if (tid >= total) return;
  int L  = tid & 63;
  int kc = (tid >> 6) % nkc;
  int ct = tid / (64 * nkc);
  int n  = ct * 16 + (L & 15);
  int kb = kc * 32 + (L >> 4) * 8;
  __hip_bfloat16* dst = out + (size_t)tid * 8;
#pragma unroll
  for (int j = 0; j < 8; ++j) {
    int kk = kb + j;
    float v = (kk < krows) ? kp[kk * ncols + n] : rp[(kk - krows) * ncols + n];
    dst[j] = __float2bfloat16(v);
  }
}

// zero the barrier flags (ws re-poisoned to 0xAA before every call).
// h1g/h2g need no init: every read is flag-gated behind its producer store.
__global__ __launch_bounds__(256) void init_state(unsigned* __restrict__ flg) {
  int idx = blockIdx.x * 256 + threadIdx.x;
  if (idx < 512) flg[idx] = 0u;
}

// ---------------------------------------------------------------------------
// Persistent recurrence kernel. Block = (rg,cg): 16 batch rows x 16 h-cols,
// 4 waves (gate-split: wave w = gate w). 8 chains of 32 blocks; rg=blockIdx&7.
// Ticket protocol: block's flag = 2t+1 after its h1_t is LLC-visible,
// = 2t+2 after its h2_t is LLC-visible. Waits: half1(t) needs all >= 2t;
// half2(t) needs all >= 2t+1. Single h buffers overwrite-safe: a block
// stores h1(t+1) only after observing all flags >= 2t+2, which requires all
// blocks consumed h1(t); same argument for h2.
// ---------------------------------------------------------------------------
__global__ __launch_bounds__(256, 1) void rnn_persist(
    const float* __restrict__ x,
    const __hip_bfloat16* __restrict__ Wp1,
    const __hip_bfloat16* __restrict__ Wp2,
    const __hip_bfloat16* __restrict__ WpP,
    const float* __restrict__ b0,
    const float* __restrict__ b1,
    const float* __restrict__ biasD,
    __hip_bfloat16* __restrict__ h1g,
    __hip_bfloat16* __restrict__ h2g,
    unsigned* __restrict__ flg,
    float* __restrict__ pred_out,
    float* __restrict__ last_out) {

  // h tiles: 1024B rows, XOR-swizzled (phys_byte = log_byte ^ ((row&7)<<4))
  __shared__ alignas(16) __hip_bfloat16 h1P[16][512];
  __shared__ alignas(16) __hip_bfloat16 h1Q[16][512];
  __shared__ alignas(16) __hip_bfloat16 h2L[16][512];
  __shared__ alignas(16) __hip_bfloat16 curL[16][72];
  __shared__ alignas(16) float predb[16][68];
  __shared__ float zb[4][16][17];

  const int tid = threadIdx.x;
  const int rg = blockIdx.x & 7;
  const int cg = blockIdx.x >> 3;
  const int w  = tid >> 6;
  const int L  = tid & 63;
  const int m  = L & 15;
  const int q  = L >> 4;
  const int row2 = tid >> 4;
  const int col2 = tid & 15;
  const int C  = cg * 16 + col2;
  const int R  = rg * 16 + row2;
  const int c0 = col2 * 4;
  const int sw = (m & 7) << 3;          // element-unit LDS read swizzle

  // per-thread 64B stage slot: row (tid>>4), bytes (tid&15)*64..+63
  const int so0 = col2 * 64;
  const int ssw = (row2 & 7) << 4;
  const size_t gso = (size_t)row2 * 1024 + so0;

  // ---- weight fragments into registers, once (gate-split layout) ----
  v8bf wpp[16], wp1[18], wp2[32];
  {
    const int ct = w * 32 + cg;
#pragma unroll
    for (int kc = 0; kc < 16; ++kc)
      wpp[kc] = ldv(WpP + ((size_t)(w * 16 + kc) * 64 + L) * 8);
#pragma unroll
    for (int kc = 0; kc < 18; ++kc)
      wp1[kc] = ldv(Wp1 + ((size_t)(ct * 18 + kc) * 64 + L) * 8);
#pragma unroll
    for (int kc = 0; kc < 32; ++kc)
      wp2[kc] = ldv(Wp2 + ((size_t)(ct * 32 + kc) * 64 + L) * 8);
  }
  const float b0i = b0[C], b0f = b0[512 + C], b0g = b0[1024 + C], b0o = b0[1536 + C];
  const float b1i = b1[C], b1f = b1[512 + C], b1g = b1[1024 + C], b1o = b1[1536 + C];
  const float bD  = biasD[w * 16 + m];

  float c1v = 0.0f, c2v = 0.0f;         // cell state in registers

  const size_t rgbase = (size_t)rg * 16 * H_;
  const float* xrow = x + (size_t)R * T_ * D_;
  float* prow = pred_out + (size_t)R * (T_ - 1) * D_;
  unsigned* fbase = flg + (rg << 6);
  const int hidx = R * H_ + C;

  // prologue: h1(-1)=0 (ping) and h2(-1)=0 directly in LDS
  {
    u32x4 zz = {0u, 0u, 0u, 0u};
    u32x4* p1 = reinterpret_cast<u32x4*>(&h1P[0][0]);
    u32x4* p2 = reinterpret_cast<u32x4*>(&h2L[0][0]);
#pragma unroll
    for (int i = 0; i < 4; ++i) { p1[tid * 4 + i] = zz; p2[tid * 4 + i] = zz; }
  }
  __syncthreads();

  // z1 h1-half accumulators, carried across the loop boundary (pipelined).
  // For t=0 the rotated-out chunks [0..8) were over h1(-1)=0 -> contribute 0.
  f32x4 z1a = {0.f,0.f,0.f,0.f}, z1b = {0.f,0.f,0.f,0.f};

  for (int t = 0; t < T_; ++t) {
    __hip_bfloat16 (*h1L)[512] = (t & 1) ? h1Q : h1P;  // h1_{t-1}
    __hip_bfloat16 (*h1N)[512] = (t & 1) ? h1P : h1Q;  // h1_t (landed below)

    const float4 xv = *reinterpret_cast<const float4*>(xrow + t * D_ + c0);

    // ---- P1: z1 h1 chunks [8..12); wave-0 polls barrier-2(t-1) ----
#pragma unroll
    for (int c = 8; c < 12; c += 2) {
      v8bf a0 = ldv(&h1L[m][(c * 32 + q * 8) ^ sw]);
      v8bf a1 = ldv(&h1L[m][((c + 1) * 32 + q * 8) ^ sw]);
      z1a = MF(a0, wp1[2 + c], z1a);
      z1b = MF(a1, wp1[3 + c], z1b);
    }
    if (t > 0 && tid < 64)
      poll_flags(fbase, L, 2u * (unsigned)t);          // all >= 2(t-1)+2
    __syncthreads();

    // ---- P2: issue h2 loads; cover with z1 h1 chunks [12..16); land ----
    u32x4 sa, sb, sc2, sd;
    if (t > 0)
      ld_llc64_issue((const char*)(h2g + rgbase) + gso, sa, sb, sc2, sd);
#pragma unroll
    for (int c = 12; c < 16; c += 2) {
      v8bf a0 = ldv(&h1L[m][(c * 32 + q * 8) ^ sw]);
      v8bf a1 = ldv(&h1L[m][((c + 1) * 32 + q * 8) ^ sw]);
      z1a = MF(a0, wp1[2 + c], z1a);
      z1b = MF(a1, wp1[3 + c], z1b);
    }
    if (t > 0) {
      vm0();
      char* lb = (char*)(&h2L[row2][0]);
      *(u32x4*)(lb + ((so0 +  0) ^ ssw)) = sa;
      *(u32x4*)(lb + ((so0 + 16) ^ ssw)) = sb;
      *(u32x4*)(lb + ((so0 + 32) ^ ssw)) = sc2;
      *(u32x4*)(lb + ((so0 + 48) ^ ssw)) = sd;
    }
    __syncthreads();

    // ---- P3: pred = h2_{t-1} @ W + bias (wave w: cols w*16..+15) ----
    if (t > 0) {
      f32x4 a0 = {0.f,0.f,0.f,0.f}, a1 = {0.f,0.f,0.f,0.f};
#pragma unroll
      for (int kc = 0; kc < 16; kc += 2) {
        v8bf x0 = ldv(&h2L[m][(kc * 32 + q * 8) ^ sw]);
        v8bf x1 = ldv(&h2L[m][((kc + 1) * 32 + q * 8) ^ sw]);
        a0 = MF(x0, wpp[kc], a0);
        a1 = MF(x1, wpp[kc + 1], a1);
      }
      a0 += a1;
#pragma unroll
      for (int r = 0; r < 4; ++r) predb[q * 4 + r][w * 16 + m] = a0[r] + bD;
    }
    __syncthreads();

    // ---- P4: cur build; cg==0 streams pred -> d_out ----
    {
      float4 pv = {0.f, 0.f, 0.f, 0.f};
      if (t > 0) pv = *reinterpret_cast<const float4*>(&predb[row2][c0]);
      const float xa[4] = {xv.x, xv.y, xv.z, xv.w};
      const float pa[4] = {pv.x, pv.y, pv.z, pv.w};
#pragma unroll
      for (int j = 0; j < 4; ++j) {
        const bool missv = (t > 0) && (xa[j] == 128.0f);
        curL[row2][c0 + j] = __float2bfloat16(missv ? pa[j] : xa[j]);
      }
      if (cg == 0 && t > 0)
        *reinterpret_cast<float4*>(prow + (size_t)(t - 1) * D_ + c0) = pv;
    }
    __syncthreads();

    // ---- P5: z1 cur-part + gate tile -> zb ----
    {
      v8bf a0 = ldv(&curL[m][q * 8]);
      v8bf a1 = ldv(&curL[m][32 + q * 8]);
      z1a = MF(a0, wp1[0], z1a);
      z1b = MF(a1, wp1[1], z1b);
      f32x4 zf = z1a + z1b;
#pragma unroll
      for (int r = 0; r < 4; ++r) zb[w][q * 4 + r][m] = zf[r];
    }
    __syncthreads();

    // ---- P6: L1 gates; h1_t store; 8 z2-h2 cover MFMAs; drain; signal ----
    f32x4 z2a = {0.f,0.f,0.f,0.f}, z2b = {0.f,0.f,0.f,0.f};
    {
      float iv = zb[0][row2][col2] + b0i;
      float fv = zb[1][row2][col2] + b0f;
      float gv = zb[2][row2][col2] + b0g;
      float ov = zb[3][row2][col2] + b0o;
      float ig = sigf(iv), fg = sigf(fv), gg = tanhfast(gv), og = sigf(ov);
      c1v = fg * c1v + ig * gg;
      float hn = og * tanhfast(c1v);
      st_llc_u16(&h1g[hidx], (unsigned)__builtin_bit_cast(unsigned short,
                                                          __float2bfloat16(hn)));
    }
#pragma unroll
    for (int c = 0; c < 8; c += 2) {           // drain cover
      v8bf a0 = ldv(&h2L[m][(c * 32 + q * 8) ^ sw]);
      v8bf a1 = ldv(&h2L[m][((c + 1) * 32 + q * 8) ^ sw]);
      z2a = MF(a0, wp2[16 + c], z2a);
      z2b = MF(a1, wp2[17 + c], z2b);
    }
    vm0();
    __syncthreads();
    if (tid == 0) st_flag(fbase + cg, 2u * (unsigned)t + 1u);

    // ---- P7: z2 h2 chunks [8..12); wave-0 polls barrier-1(t) ----
#pragma unroll
    for (int c = 8; c < 12; c += 2) {
      v8bf a0 = ldv(&h2L[m][(c * 32 + q * 8) ^ sw]);
      v8bf a1 = ldv(&h2L[m][((c + 1) * 32 + q * 8) ^ sw]);
      z2a = MF(a0, wp2[16 + c], z2a);
      z2b = MF(a1, wp2[17 + c], z2b);
    }
    if (tid < 64)
      poll_flags(fbase, L, 2u * (unsigned)t + 1u);
    __syncthreads();

    // ---- P8: issue h1_t loads; cover with z2 h2 chunks [12..16); land ----
    ld_llc64_issue((const char*)(h1g + rgbase) + gso, sa, sb, sc2, sd);
#pragma unroll
    for (int c = 12; c < 16; c += 2) {
      v8bf a0 = ldv(&h2L[m][(c * 32 + q * 8) ^ sw]);
      v8bf a1 = ldv(&h2L[m][((c + 1) * 32 + q * 8) ^ sw]);
      z2a = MF(a0, wp2[16 + c], z2a);
      z2b = MF(a1, wp2[17 + c], z2b);
    }
    vm0();
    {
      char* lb = (char*)(&h1N[row2][0]);
      *(u32x4*)(lb + ((so0 +  0) ^ ssw)) = sa;
      *(u32x4*)(lb + ((so0 + 16) ^ ssw)) = sb;
      *(u32x4*)(lb + ((so0 + 32) ^ ssw)) = sc2;
      *(u32x4*)(lb + ((so0 + 48) ^ ssw)) = sd;
    }
    __syncthreads();

    // ---- P9: z2 h1-half + gate tile -> zb ----
    {
#pragma unroll
      for (int c = 0; c < 16; c += 2) {
        v8bf a0 = ldv(&h1N[m][(c * 32 + q * 8) ^ sw]);
        v8bf a1 = ldv(&h1N[m][((c + 1) * 32 + q * 8) ^ sw]);
        z2a = MF(a0, wp2[c], z2a);
        z2b = MF(a1, wp2[c + 1], z2b);
      }
      f32x4 zf = z2a + z2b;
#pragma unroll
      for (int r = 0; r < 4; ++r) zb[w][q * 4 + r][m] = zf[r];
    }
    __syncthreads();

    // ---- P10: L2 gates; h2_t store (or last_cell); next-step z1 cover;
    //           drain; signal barrier-2 ----
    {
      float iv = zb[0][row2][col2] + b1i;
      float fv = zb[1][row2][col2] + b1f;
      float gv = zb[2][row2][col2] + b1g;
      float ov = zb[3][row2][col2] + b1o;
      float ig = sigf(iv), fg = sigf(fv), gg = tanhfast(gv), og = sigf(ov);
      c2v = fg * c2v + ig * gg;
      float hn = og * tanhfast(c2v);
      if (t == T_ - 1) {
        last_out[hidx] = hn;
        break;
      }
      st_llc_u16(&h2g[hidx], (unsigned)__builtin_bit_cast(unsigned short,
                                                          __float2bfloat16(hn)));
    }
    // next step's z1 h1 chunks [0..8) over h1N (= h1_t), hiding the drain
    z1a = (f32x4){0.f,0.f,0.f,0.f};
    z1b = (f32x4){0.f,0.f,0.f,0.f};
#pragma unroll
    for (int c = 0; c < 8; c += 2) {
      v8bf a0 = ldv(&h1N[m][(c * 32 + q * 8) ^ sw]);
      v8bf a1 = ldv(&h1N[m][((c + 1) * 32 + q * 8) ^ sw]);
      z1a = MF(a0, wp1[2 + c], z1a);
      z1b = MF(a1, wp1[3 + c], z1b);
    }
    vm0();
    __syncthreads();
    if (tid == 0) st_flag(fbase + cg, 2u * (unsigned)t + 2u);
  }
}

// ---------------------------------------------------------------------------
extern "C" void kernel_launch(void* const* d_in, const int* in_sizes, int n_in,
                              void* d_out, int out_size, void* d_ws, size_t ws_size,
                              hipStream_t stream) {
  const float* x    = (const float*)d_in[0];
  const float* k0   = (const float*)d_in[1];
  const float* r0   = (const float*)d_in[2];
  const float* b0   = (const float*)d_in[3];
  const float* k1   = (const float*)d_in[4];
  const float* r1   = (const float*)d_in[5];
  const float* b1   = (const float*)d_in[6];
  const float* W    = (const float*)d_in[7];
  const float* bias = (const float*)d_in[8];

  char* ws = (char*)d_ws;
  __hip_bfloat16* Wp1 = (__hip_bfloat16*)(ws + OFF_WP1);
  __hip_bfloat16* Wp2 = (__hip_bfloat16*)(ws + OFF_WP2);
  __hip_bfloat16* WpP = (__hip_bfloat16*)(ws + OFF_WPP);
  __hip_bfloat16* h1g = (__hip_bfloat16*)(ws + OFF_H1G);
  __hip_bfloat16* h2g = (__hip_bfloat16*)(ws + OFF_H2G);
  unsigned*       flg = (unsigned*)(ws + OFF_FLG);

  pack_weights<<<(128 * 18 * 64 + 255) / 256, 256, 0, stream>>>(k0, r0, 64, 2048, 18, 128, Wp1);
  pack_weights<<<(128 * 32 * 64 + 255) / 256, 256, 0, stream>>>(k1, r1, 512, 2048, 32, 128, Wp2);
  pack_weights<<<(4 * 16 * 64 + 255) / 256, 256, 0, stream>>>(W, W, 512, 64, 16, 4, WpP);
  init_state<<<2, 256, 0, stream>>>(flg);

  float* outp = (float*)d_out;
  float* last = outp + (size_t)B_ * (T_ - 1) * D_;

  rnn_persist<<<256, 256, 0, stream>>>(x, Wp1, Wp2, WpP, b0, b1, bias,
                                       h1g, h2g, flg, outp, last);
}